// Round 5
// baseline (458.887 us; speedup 1.0000x reference)
//
#include <hip/hip_runtime.h>
#include <hip/hip_bf16.h>
#include <float.h>

// z: (64, 256, 32, 32) fp32 ; emb: (1024, 256) fp32
// M = 65536 pixels, D = 256, K = 1024 codes
// out: [z_q (16777216 f)] [indices as float (65536)] [vq_loss (1)]
#define OUT_IDX_OFF 16777216
#define OUT_LOSS_OFF 16842752
// scratch inside d_out's z_q region (overwritten by k_out at the end):
// A2 bf16 (row-major [pixel][256]): floats [0, 8388608)
// cand pairs (s,k) float2: floats [8388608, 12582912)  65536 rows x 32 slots
// gmin (int-punned f32):   floats [12582912, 13107200)
// gcnt (int):              floats [13107200, 13631488)
#define CAND_OFF 8388608
#define GMIN_OFF 12582912
#define GCNT_OFF 13107200
#define NSLOT 32
#define DELTA 2.0e-3f

typedef __attribute__((ext_vector_type(8))) short short8;
typedef __attribute__((ext_vector_type(4))) float f32x4;

static __device__ __forceinline__ unsigned short f2bf(float f) {
  union { __hip_bfloat16 h; unsigned short u; } cv;
  cv.h = __float2bfloat16(f);
  return cv.u;
}

// ---------------------------------------------------------------------------
// P1: emb -> E2 bf16 [1024 codes][256 d] row-major + exact cws (proven).
// ---------------------------------------------------------------------------
__global__ __launch_bounds__(256) void k_prep(const float* __restrict__ emb,
                                              unsigned short* __restrict__ E2,
                                              float* __restrict__ cws) {
  const int k = blockIdx.x, d = threadIdx.x;
  const float v = emb[k * 256 + d];
  __shared__ float red[256];
  __shared__ unsigned short row[256];
  row[d] = f2bf(v);
  red[d] = v * v;
  __syncthreads();
  for (int s = 128; s > 0; s >>= 1) {
    if (d < s) red[d] += red[d + s];
    __syncthreads();
  }
  if (d == 0) cws[k] = red[0];
  if (d < 32) ((short8*)&E2[k * 256])[d] = ((short8*)row)[d];
}

// ---------------------------------------------------------------------------
// k_cvt4: FUSED z->A2 bf16 (row-major) + exact aws (k_a absorbed). Proven in
// R4 (rest-of-pipeline -17us, bit-exact aws). Unchanged.
// ---------------------------------------------------------------------------
__global__ __launch_bounds__(256) void k_cvt4(const float* __restrict__ z,
                                              unsigned short* __restrict__ A2,
                                              float* __restrict__ aws) {
#pragma clang fp contract(off)
  __shared__ float tile[64][65];
  __shared__ float red2[128];
  const int t = threadIdx.x;
  const int p0 = blockIdx.x << 6;
  const int n = p0 >> 10, hw0 = p0 & 1023;
  const float* zb = z + (size_t)n * 262144 + hw0;
  const int hwl = (t & 15) << 2;
  const int dlb = t >> 4;  // 0..15
  const int row = t & 63, h = (t >> 6) & 1;  // acc assignment (t<128)
  const int pl = t >> 2, c = t & 3;          // A2-store assignment

  float4 v[4];
#pragma unroll
  for (int i = 0; i < 4; ++i)
    v[i] = *(const float4*)&zb[(size_t)(dlb + i * 16) * 1024 + hwl];

  float acc[8];

  for (int dt = 0; dt < 4; ++dt) {
    if (dt) __syncthreads();  // previous-phase readers done
#pragma unroll
    for (int i = 0; i < 4; ++i) {
      const int dl = dlb + i * 16;
      tile[hwl + 0][dl] = v[i].x;
      tile[hwl + 1][dl] = v[i].y;
      tile[hwl + 2][dl] = v[i].z;
      tile[hwl + 3][dl] = v[i].w;
    }
    __syncthreads();
    if (dt < 3) {  // prefetch next slab into regs (overlaps phase below)
      const float* zb2 = zb + (size_t)(dt + 1) * 65536;
#pragma unroll
      for (int i = 0; i < 4; ++i)
        v[i] = *(const float4*)&zb2[(size_t)(dlb + i * 16) * 1024 + hwl];
    }
    // A2 store (verbatim k_cvt2 store phase, d0 = dt*64)
    unsigned short* dst = &A2[(size_t)(p0 + pl) * 256 + dt * 64];
#pragma unroll
    for (int hh = 0; hh < 2; ++hh) {
      const int ch = c + hh * 4;
      unsigned short tmp[8];
#pragma unroll
      for (int j = 0; j < 8; ++j) tmp[j] = f2bf(tile[pl][ch * 8 + j]);
      *(short8*)&dst[ch * 8] = *(short8*)tmp;
    }
    // aws chain: wave0 (h=0) consumes slabs 0,1; wave1 (h=1) slabs 2,3
    if (t < 128 && (dt >> 1) == h) {
      if ((dt & 1) == 0) {
#pragma unroll
        for (int j = 0; j < 8; ++j) {
          const float x = tile[row][j];
          acc[j] = x * x;  // g = 0 init
        }
        for (int g = 1; g < 8; ++g)
#pragma unroll
          for (int j = 0; j < 8; ++j) {
            const float x = tile[row][g * 8 + j];
            const float p = x * x;
            acc[j] = acc[j] + p;
          }
      } else {
        for (int g = 8; g < 16; ++g)
#pragma unroll
          for (int j = 0; j < 8; ++j) {
            const float x = tile[row][(g - 8) * 8 + j];
            const float p = x * x;
            acc[j] = acc[j] + p;
          }
      }
    }
  }
  if (t < 128) {
    const float s = ((acc[0] + acc[1]) + (acc[2] + acc[3])) +
                    ((acc[4] + acc[5]) + (acc[6] + acc[7]));
    red2[t] = s;
  }
  __syncthreads();
  if (t < 64) aws[p0 + t] = red2[t] + red2[t + 64];  // fl(s_h0 + s_h1), as k_a
}

// ---------------------------------------------------------------------------
// k_gemm7: k_gemm4 (proven 96.5us) with LDS shrunk to EXACTLY 32KB so 5
// blocks/CU fit (163840/32768 = 5; was 4 at 35328B).  dur*occ ~= 3000 (pure
// latency-bound, R0-R4 evidence) => +25% residency => ~78us predicted.
//   - a_l/c_l LDS copies removed: epilogue reads aws[r0+..]/cws[k0+..]
//     directly (same bits; quad-uniform addresses -> L1 broadcast).
//   - rmkt/bmin aliased into the tile buffer AFTER a new post-loop barrier
//     (tiles dead by then; pass1/pass2 barrier structure unchanged).
//   - staging, XCD swizzle, MFMA order (kt 0..3, ks 0..1, tr, tc), score
//     chain, atomics: verbatim k_gemm4 -> bit-identical gmin/candidates.
// ---------------------------------------------------------------------------
__global__ __launch_bounds__(256, 5) void k_gemm7(
    const unsigned short* __restrict__ A2, const unsigned short* __restrict__ E2,
    const float* __restrict__ cws, const float* __restrict__ aws,
    int* __restrict__ gmin, int* __restrict__ gcnt,
    float2* __restrict__ gcand) {
  __shared__ __align__(16) unsigned short smem[16384];  // 32768 B exactly
  unsigned short* As = smem;          // [128*64]
  unsigned short* Bs = smem + 8192;   // [128*64]
  float* rmkt = (float*)smem;         // epilogue alias: 256 floats
  float* bmin = ((float*)smem) + 256; // epilogue alias: 128 floats

  const int t = threadIdx.x;
  const int lane = t & 63;
  const int wave = __builtin_amdgcn_readfirstlane(t >> 6);
  const int wr = wave >> 1, wc = wave & 1;
  const int quad = lane >> 4, l15 = lane & 15;
  const int swa = l15 & 7;

  // XCD-chunked swizzle (grid 4096 % 8 == 0 -> bijective)
  const int bid = blockIdx.x;
  const int L = ((bid & 7) << 9) + (bid >> 3);
  const int rb = L >> 3, ck = L & 7;
  const int r0 = rb << 7, k0 = ck << 7;

  // staging geometry (verbatim k_gemm4): round i covers granules G=i*256+t;
  // row = G>>3, physical granule gpos = G&7, source granule gpos^(row&7).
  const int srow = t >> 3;
  const int gpos = t & 7;

  f32x4 acc[4][4];
#pragma unroll
  for (int a = 0; a < 4; ++a)
#pragma unroll
    for (int b = 0; b < 4; ++b) acc[a][b] = (f32x4)(0.0f);

  for (int kt = 0; kt < 4; ++kt) {
    if (kt) __syncthreads();  // waves done reading previous tiles
#pragma unroll
    for (int i = 0; i < 4; ++i) {
      const int row = (i << 5) + srow;
      const int gsrc = gpos ^ (row & 7);
      const unsigned short* sa =
          A2 + (((size_t)(r0 + row)) << 8) + (kt << 6) + (gsrc << 3);
      __builtin_amdgcn_global_load_lds(
          (const __attribute__((address_space(1))) void*)sa,
          (__attribute__((address_space(3))) void*)(As + (i << 11) +
                                                    (wave << 9)),
          16, 0, 0);
      const unsigned short* sb =
          E2 + (((size_t)(k0 + row)) << 8) + (kt << 6) + (gsrc << 3);
      __builtin_amdgcn_global_load_lds(
          (const __attribute__((address_space(1))) void*)sb,
          (__attribute__((address_space(3))) void*)(Bs + (i << 11) +
                                                    (wave << 9)),
          16, 0, 0);
    }
    __syncthreads();  // vmcnt drained -> tiles ready
#pragma unroll
    for (int ks = 0; ks < 2; ++ks) {
      short8 af[4], bf[4];
#pragma unroll
      for (int tr = 0; tr < 4; ++tr)
        af[tr] = *(const short8*)&As[(wr * 64 + tr * 16 + l15) * 64 +
                                     (((ks * 4 + quad) ^ swa) << 3)];
#pragma unroll
      for (int tc = 0; tc < 4; ++tc)
        bf[tc] = *(const short8*)&Bs[(wc * 64 + tc * 16 + l15) * 64 +
                                     (((ks * 4 + quad) ^ swa) << 3)];
#pragma unroll
      for (int tr = 0; tr < 4; ++tr)
#pragma unroll
        for (int tc = 0; tc < 4; ++tc)
          acc[tr][tc] = __builtin_amdgcn_mfma_f32_16x16x32_bf16(
              af[tr], bf[tc], acc[tr][tc], 0, 0, 0);
    }
  }
  __syncthreads();  // tiles dead; epilogue may now alias rmkt/bmin onto smem

  // epilogue pass 1: chunk-local per-row min (score chain verbatim; av/c
  // from global instead of LDS copies -- identical bits)
#pragma unroll
  for (int tr = 0; tr < 4; ++tr)
#pragma unroll
    for (int rg = 0; rg < 4; ++rg) {
      const int rloc = wr * 64 + tr * 16 + quad * 4 + rg;
      const float av = aws[r0 + rloc];
      float mn = FLT_MAX;
#pragma unroll
      for (int tc = 0; tc < 4; ++tc) {
        const int cloc = wc * 64 + tc * 16 + l15;
        const float s = av + fmaf(-2.0f, acc[tr][tc][rg], cws[k0 + cloc]);
        mn = fminf(mn, s);
      }
      mn = fminf(mn, __shfl_xor(mn, 1));
      mn = fminf(mn, __shfl_xor(mn, 2));
      mn = fminf(mn, __shfl_xor(mn, 4));
      mn = fminf(mn, __shfl_xor(mn, 8));
      if (l15 == 0) rmkt[rloc * 2 + wc] = mn;
    }
  __syncthreads();
  if (t < 128) {
    const float m = fminf(rmkt[t * 2], rmkt[t * 2 + 1]);
    const int old = atomicMin(&gmin[r0 + t], __float_as_int(m));
    bmin[t] = fminf(m, __int_as_float(old));  // bits monotone for s>0
  }
  __syncthreads();
  // epilogue pass 2: append candidates within DELTA of tightened min
#pragma unroll
  for (int tr = 0; tr < 4; ++tr)
#pragma unroll
    for (int rg = 0; rg < 4; ++rg) {
      const int rloc = wr * 64 + tr * 16 + quad * 4 + rg;
      const float av = aws[r0 + rloc];
      const float lim = bmin[rloc] + DELTA;
#pragma unroll
      for (int tc = 0; tc < 4; ++tc) {
        const int cloc = wc * 64 + tc * 16 + l15;
        const float s = av + fmaf(-2.0f, acc[tr][tc][rg], cws[k0 + cloc]);
        if (s <= lim) {
          const int pos = atomicAdd(&gcnt[r0 + rloc], 1);
          if (pos < NSLOT)
            gcand[(size_t)(r0 + rloc) * NSLOT + pos] =
                make_float2(s, __int_as_float(k0 + cloc));
        }
      }
    }
}

// ---------------------------------------------------------------------------
// k_finish v2: 4 lanes per row, exact rescore chain UNCHANGED (bit-identical
// scores -> identical indices), quad shuffle-reduce with strict-< + lowest-k.
// Also accumulates vq_loss: winner's s IS ||z-e||^2 for that row.
// ---------------------------------------------------------------------------
__global__ __launch_bounds__(256) void k_finish(
    const float* __restrict__ z, const float* __restrict__ emb,
    const float* __restrict__ cws, const float* __restrict__ aws,
    const int* __restrict__ gmin, const int* __restrict__ gcnt,
    const float2* __restrict__ gcand, int* __restrict__ idxws,
    float* __restrict__ out) {
  const int tid = (blockIdx.x << 8) + threadIdx.x;
  const int r = tid >> 2, sub = tid & 3;
  const float lim = __int_as_float(gmin[r]) + DELTA;
  int m = gcnt[r];
  if (m > NSLOT) m = NSLOT;
  const int n = r >> 10, hw = r & 1023;
  const float* zp = z + (size_t)n * 262144 + hw;
  const float a = aws[r];
  float bestv = FLT_MAX;
  int besti = 0x7fffffff;
  for (int ci = sub; ci < m; ci += 4) {
    const float2 p = gcand[(size_t)r * NSLOT + ci];
    if (p.x > lim) continue;
    const int k = __float_as_int(p.y);
    const float* ep = emb + (size_t)k * 256;
    float dot = 0.0f;
#pragma unroll 8
    for (int d = 0; d < 256; ++d) dot = fmaf(zp[(size_t)d * 1024], ep[d], dot);
    float s = fmaf(-2.0f, dot, a);  // fl(a - 2*dot)
    s = s + cws[k];                 // fl(s + c)
    if (s < bestv || (s == bestv && k < besti)) {
      bestv = s;
      besti = k;
    }
  }
#pragma unroll
  for (int off = 1; off < 4; off <<= 1) {
    const float ov = __shfl_xor(bestv, off);
    const int oi = __shfl_xor(besti, off);
    if (ov < bestv || (ov == bestv && oi < besti)) {
      bestv = ov;
      besti = oi;
    }
  }
  if (sub == 0) {
    idxws[r] = besti;
    out[OUT_IDX_OFF + r] = (float)besti;
  }
  float c = (sub == 0) ? bestv : 0.0f;
#pragma unroll
  for (int off = 1; off < 64; off <<= 1) c += __shfl_xor(c, off);
  if ((threadIdx.x & 63) == 0)
    atomicAdd(&out[OUT_LOSS_OFF], c * (1.02f / 16777216.0f));
}

// ---------------------------------------------------------------------------
// k_out2: pure z_q gather-write (unchanged). Overwrites all d_out scratch.
// ---------------------------------------------------------------------------
__global__ __launch_bounds__(256) void k_out2(const float* __restrict__ emb,
                                              const int* __restrict__ idxws,
                                              float* __restrict__ out) {
  __shared__ float zq[32][257];
  __shared__ int sidx[32];
  const int t = threadIdx.x;
  const int p0 = blockIdx.x << 5;
  const int n = p0 >> 10, hw0 = p0 & 1023;
  if (t < 32) sidx[t] = idxws[p0 + t];
  __syncthreads();
#pragma unroll
  for (int it = 0; it < 8; ++it) {
    const int i = t + (it << 8);
    const int p = i >> 6;
    const int q = (i & 63) << 2;
    const float4 v = *(const float4*)&emb[(size_t)sidx[p] * 256 + q];
    zq[p][q] = v.x;
    zq[p][q + 1] = v.y;
    zq[p][q + 2] = v.z;
    zq[p][q + 3] = v.w;
  }
  __syncthreads();
  const int p = t & 31, d0 = t >> 5;
  float* ob = out + (size_t)n * 262144 + hw0 + p;
#pragma unroll
  for (int dd = 0; dd < 32; ++dd) {
    const int d = (dd << 3) + d0;
    ob[(size_t)d * 1024] = zq[p][d];
  }
}

// ---------------------------------------------------------------------------
extern "C" void kernel_launch(void* const* d_in, const int* in_sizes, int n_in,
                              void* d_out, int out_size, void* d_ws,
                              size_t ws_size, hipStream_t stream) {
  const float* z = (const float*)d_in[0];
  const float* emb = (const float*)d_in[1];
  float* out = (float*)d_out;

  // ws layout: E2 bf16 [1024*256] | cws [1024] | aws [65536] | idx [65536]
  unsigned short* E2 = (unsigned short*)d_ws;
  float* cws = (float*)(E2 + 262144);
  float* aws = cws + 1024;
  int* idxws = (int*)(aws + 65536);
  // scratch in d_out's z_q region (k_out2 overwrites it last):
  unsigned short* A2 = (unsigned short*)d_out;
  float2* gcand = (float2*)(out + CAND_OFF);
  int* gmin = (int*)(out + GMIN_OFF);
  int* gcnt = (int*)(out + GCNT_OFF);

  hipMemsetAsync((char*)d_out + (size_t)OUT_LOSS_OFF * 4, 0, 4, stream);
  hipMemsetAsync(gmin, 0x7f, 65536 * 4, stream);  // 0x7f7f7f7f ~ +inf
  hipMemsetAsync(gcnt, 0, 65536 * 4, stream);

  k_prep<<<dim3(1024), dim3(256), 0, stream>>>(emb, E2, cws);
  k_cvt4<<<dim3(1024), dim3(256), 0, stream>>>(z, A2, aws);
  k_gemm7<<<dim3(4096), dim3(256), 0, stream>>>(A2, E2, cws, aws, gmin, gcnt,
                                                gcand);
  k_finish<<<dim3(1024), dim3(256), 0, stream>>>(z, emb, cws, aws, gmin, gcnt,
                                                 gcand, idxws, out);
  k_out2<<<dim3(2048), dim3(256), 0, stream>>>(emb, idxws, out);
}

// Round 6
// 364.221 us; speedup vs baseline: 1.2599x; 1.2599x over previous
//
#include <hip/hip_runtime.h>
#include <hip/hip_bf16.h>
#include <float.h>

// z: (64, 256, 32, 32) fp32 ; emb: (1024, 256) fp32
// M = 65536 pixels, D = 256, K = 1024 codes
// out: [z_q (16777216 f)] [indices as float (65536)] [vq_loss (1)]
#define OUT_IDX_OFF 16777216
#define OUT_LOSS_OFF 16842752
// scratch inside d_out's z_q region (overwritten by k_out at the end):
// A2 bf16 (row-major [pixel][256]): floats [0, 8388608)
// cand pairs (s,k) float2: floats [8388608, 12582912)  65536 rows x 32 slots
// gmin (int-punned f32):   floats [12582912, 13107200)
// gcnt (int):              floats [13107200, 13631488)
#define CAND_OFF 8388608
#define GMIN_OFF 12582912
#define GCNT_OFF 13107200
#define NSLOT 32
#define DELTA 2.0e-3f

typedef __attribute__((ext_vector_type(8))) short short8;
typedef __attribute__((ext_vector_type(4))) float f32x4;

static __device__ __forceinline__ unsigned short f2bf(float f) {
  union { __hip_bfloat16 h; unsigned short u; } cv;
  cv.h = __float2bfloat16(f);
  return cv.u;
}

// ---------------------------------------------------------------------------
// P1: emb -> E2 bf16 [1024 codes][256 d] row-major + exact cws (proven).
// ---------------------------------------------------------------------------
__global__ __launch_bounds__(256) void k_prep(const float* __restrict__ emb,
                                              unsigned short* __restrict__ E2,
                                              float* __restrict__ cws) {
  const int k = blockIdx.x, d = threadIdx.x;
  const float v = emb[k * 256 + d];
  __shared__ float red[256];
  __shared__ unsigned short row[256];
  row[d] = f2bf(v);
  red[d] = v * v;
  __syncthreads();
  for (int s = 128; s > 0; s >>= 1) {
    if (d < s) red[d] += red[d + s];
    __syncthreads();
  }
  if (d == 0) cws[k] = red[0];
  if (d < 32) ((short8*)&E2[k * 256])[d] = ((short8*)row)[d];
}

// ---------------------------------------------------------------------------
// k_cvt4: FUSED z->A2 bf16 (row-major) + exact aws (k_a absorbed). Proven in
// R4 (rest-of-pipeline -17us, bit-exact aws). Unchanged.
// ---------------------------------------------------------------------------
__global__ __launch_bounds__(256) void k_cvt4(const float* __restrict__ z,
                                              unsigned short* __restrict__ A2,
                                              float* __restrict__ aws) {
#pragma clang fp contract(off)
  __shared__ float tile[64][65];
  __shared__ float red2[128];
  const int t = threadIdx.x;
  const int p0 = blockIdx.x << 6;
  const int n = p0 >> 10, hw0 = p0 & 1023;
  const float* zb = z + (size_t)n * 262144 + hw0;
  const int hwl = (t & 15) << 2;
  const int dlb = t >> 4;  // 0..15
  const int row = t & 63, h = (t >> 6) & 1;  // acc assignment (t<128)
  const int pl = t >> 2, c = t & 3;          // A2-store assignment

  float4 v[4];
#pragma unroll
  for (int i = 0; i < 4; ++i)
    v[i] = *(const float4*)&zb[(size_t)(dlb + i * 16) * 1024 + hwl];

  float acc[8];

  for (int dt = 0; dt < 4; ++dt) {
    if (dt) __syncthreads();  // previous-phase readers done
#pragma unroll
    for (int i = 0; i < 4; ++i) {
      const int dl = dlb + i * 16;
      tile[hwl + 0][dl] = v[i].x;
      tile[hwl + 1][dl] = v[i].y;
      tile[hwl + 2][dl] = v[i].z;
      tile[hwl + 3][dl] = v[i].w;
    }
    __syncthreads();
    if (dt < 3) {  // prefetch next slab into regs (overlaps phase below)
      const float* zb2 = zb + (size_t)(dt + 1) * 65536;
#pragma unroll
      for (int i = 0; i < 4; ++i)
        v[i] = *(const float4*)&zb2[(size_t)(dlb + i * 16) * 1024 + hwl];
    }
    // A2 store (verbatim k_cvt2 store phase, d0 = dt*64)
    unsigned short* dst = &A2[(size_t)(p0 + pl) * 256 + dt * 64];
#pragma unroll
    for (int hh = 0; hh < 2; ++hh) {
      const int ch = c + hh * 4;
      unsigned short tmp[8];
#pragma unroll
      for (int j = 0; j < 8; ++j) tmp[j] = f2bf(tile[pl][ch * 8 + j]);
      *(short8*)&dst[ch * 8] = *(short8*)tmp;
    }
    // aws chain: wave0 (h=0) consumes slabs 0,1; wave1 (h=1) slabs 2,3
    if (t < 128 && (dt >> 1) == h) {
      if ((dt & 1) == 0) {
#pragma unroll
        for (int j = 0; j < 8; ++j) {
          const float x = tile[row][j];
          acc[j] = x * x;  // g = 0 init
        }
        for (int g = 1; g < 8; ++g)
#pragma unroll
          for (int j = 0; j < 8; ++j) {
            const float x = tile[row][g * 8 + j];
            const float p = x * x;
            acc[j] = acc[j] + p;
          }
      } else {
        for (int g = 8; g < 16; ++g)
#pragma unroll
          for (int j = 0; j < 8; ++j) {
            const float x = tile[row][(g - 8) * 8 + j];
            const float p = x * x;
            acc[j] = acc[j] + p;
          }
      }
    }
  }
  if (t < 128) {
    const float s = ((acc[0] + acc[1]) + (acc[2] + acc[3])) +
                    ((acc[4] + acc[5]) + (acc[6] + acc[7]));
    red2[t] = s;
  }
  __syncthreads();
  if (t < 64) aws[p0 + t] = red2[t] + red2[t + 64];  // fl(s_h0 + s_h1), as k_a
}

// ---------------------------------------------------------------------------
// k_gemm8: k_gemm7 with the launch bound relaxed to (256,4).
// R5's (256,5) promise capped VGPRs at ~102 and SPILLED the 64-VGPR
// accumulator to scratch (VGPR_Count=48, WRITE_SIZE 542MB, 257us).
// With (256,4) the compiler allocates ~64-72 VGPRs (no spill) and the
// HARDWARE still fits 5 blocks/CU: LDS 32768*5 = 160KB exactly, VGPR<=102.
// Staging, XCD swizzle, MFMA order, score chain, atomics: verbatim k_gemm4
// -> bit-identical gmin/candidates (R5 already validated this code path).
// ---------------------------------------------------------------------------
__global__ __launch_bounds__(256, 4) void k_gemm8(
    const unsigned short* __restrict__ A2, const unsigned short* __restrict__ E2,
    const float* __restrict__ cws, const float* __restrict__ aws,
    int* __restrict__ gmin, int* __restrict__ gcnt,
    float2* __restrict__ gcand) {
  __shared__ __align__(16) unsigned short smem[16384];  // 32768 B exactly
  unsigned short* As = smem;          // [128*64]
  unsigned short* Bs = smem + 8192;   // [128*64]
  float* rmkt = (float*)smem;         // epilogue alias: 256 floats
  float* bmin = ((float*)smem) + 256; // epilogue alias: 128 floats

  const int t = threadIdx.x;
  const int lane = t & 63;
  const int wave = __builtin_amdgcn_readfirstlane(t >> 6);
  const int wr = wave >> 1, wc = wave & 1;
  const int quad = lane >> 4, l15 = lane & 15;
  const int swa = l15 & 7;

  // XCD-chunked swizzle (grid 4096 % 8 == 0 -> bijective)
  const int bid = blockIdx.x;
  const int L = ((bid & 7) << 9) + (bid >> 3);
  const int rb = L >> 3, ck = L & 7;
  const int r0 = rb << 7, k0 = ck << 7;

  // staging geometry (verbatim k_gemm4): round i covers granules G=i*256+t;
  // row = G>>3, physical granule gpos = G&7, source granule gpos^(row&7).
  const int srow = t >> 3;
  const int gpos = t & 7;

  f32x4 acc[4][4];
#pragma unroll
  for (int a = 0; a < 4; ++a)
#pragma unroll
    for (int b = 0; b < 4; ++b) acc[a][b] = (f32x4)(0.0f);

  for (int kt = 0; kt < 4; ++kt) {
    if (kt) __syncthreads();  // waves done reading previous tiles
#pragma unroll
    for (int i = 0; i < 4; ++i) {
      const int row = (i << 5) + srow;
      const int gsrc = gpos ^ (row & 7);
      const unsigned short* sa =
          A2 + (((size_t)(r0 + row)) << 8) + (kt << 6) + (gsrc << 3);
      __builtin_amdgcn_global_load_lds(
          (const __attribute__((address_space(1))) void*)sa,
          (__attribute__((address_space(3))) void*)(As + (i << 11) +
                                                    (wave << 9)),
          16, 0, 0);
      const unsigned short* sb =
          E2 + (((size_t)(k0 + row)) << 8) + (kt << 6) + (gsrc << 3);
      __builtin_amdgcn_global_load_lds(
          (const __attribute__((address_space(1))) void*)sb,
          (__attribute__((address_space(3))) void*)(Bs + (i << 11) +
                                                    (wave << 9)),
          16, 0, 0);
    }
    __syncthreads();  // vmcnt drained -> tiles ready
#pragma unroll
    for (int ks = 0; ks < 2; ++ks) {
      short8 af[4], bf[4];
#pragma unroll
      for (int tr = 0; tr < 4; ++tr)
        af[tr] = *(const short8*)&As[(wr * 64 + tr * 16 + l15) * 64 +
                                     (((ks * 4 + quad) ^ swa) << 3)];
#pragma unroll
      for (int tc = 0; tc < 4; ++tc)
        bf[tc] = *(const short8*)&Bs[(wc * 64 + tc * 16 + l15) * 64 +
                                     (((ks * 4 + quad) ^ swa) << 3)];
#pragma unroll
      for (int tr = 0; tr < 4; ++tr)
#pragma unroll
        for (int tc = 0; tc < 4; ++tc)
          acc[tr][tc] = __builtin_amdgcn_mfma_f32_16x16x32_bf16(
              af[tr], bf[tc], acc[tr][tc], 0, 0, 0);
    }
  }
  __syncthreads();  // tiles dead; epilogue may now alias rmkt/bmin onto smem

  // epilogue pass 1: chunk-local per-row min (score chain verbatim; av/c
  // from global instead of LDS copies -- identical bits)
#pragma unroll
  for (int tr = 0; tr < 4; ++tr)
#pragma unroll
    for (int rg = 0; rg < 4; ++rg) {
      const int rloc = wr * 64 + tr * 16 + quad * 4 + rg;
      const float av = aws[r0 + rloc];
      float mn = FLT_MAX;
#pragma unroll
      for (int tc = 0; tc < 4; ++tc) {
        const int cloc = wc * 64 + tc * 16 + l15;
        const float s = av + fmaf(-2.0f, acc[tr][tc][rg], cws[k0 + cloc]);
        mn = fminf(mn, s);
      }
      mn = fminf(mn, __shfl_xor(mn, 1));
      mn = fminf(mn, __shfl_xor(mn, 2));
      mn = fminf(mn, __shfl_xor(mn, 4));
      mn = fminf(mn, __shfl_xor(mn, 8));
      if (l15 == 0) rmkt[rloc * 2 + wc] = mn;
    }
  __syncthreads();
  if (t < 128) {
    const float m = fminf(rmkt[t * 2], rmkt[t * 2 + 1]);
    const int old = atomicMin(&gmin[r0 + t], __float_as_int(m));
    bmin[t] = fminf(m, __int_as_float(old));  // bits monotone for s>0
  }
  __syncthreads();
  // epilogue pass 2: append candidates within DELTA of tightened min
#pragma unroll
  for (int tr = 0; tr < 4; ++tr)
#pragma unroll
    for (int rg = 0; rg < 4; ++rg) {
      const int rloc = wr * 64 + tr * 16 + quad * 4 + rg;
      const float av = aws[r0 + rloc];
      const float lim = bmin[rloc] + DELTA;
#pragma unroll
      for (int tc = 0; tc < 4; ++tc) {
        const int cloc = wc * 64 + tc * 16 + l15;
        const float s = av + fmaf(-2.0f, acc[tr][tc][rg], cws[k0 + cloc]);
        if (s <= lim) {
          const int pos = atomicAdd(&gcnt[r0 + rloc], 1);
          if (pos < NSLOT)
            gcand[(size_t)(r0 + rloc) * NSLOT + pos] =
                make_float2(s, __int_as_float(k0 + cloc));
        }
      }
    }
}

// ---------------------------------------------------------------------------
// k_finish v2: 4 lanes per row, exact rescore chain UNCHANGED (bit-identical
// scores -> identical indices), quad shuffle-reduce with strict-< + lowest-k.
// Also accumulates vq_loss: winner's s IS ||z-e||^2 for that row.
// ---------------------------------------------------------------------------
__global__ __launch_bounds__(256) void k_finish(
    const float* __restrict__ z, const float* __restrict__ emb,
    const float* __restrict__ cws, const float* __restrict__ aws,
    const int* __restrict__ gmin, const int* __restrict__ gcnt,
    const float2* __restrict__ gcand, int* __restrict__ idxws,
    float* __restrict__ out) {
  const int tid = (blockIdx.x << 8) + threadIdx.x;
  const int r = tid >> 2, sub = tid & 3;
  const float lim = __int_as_float(gmin[r]) + DELTA;
  int m = gcnt[r];
  if (m > NSLOT) m = NSLOT;
  const int n = r >> 10, hw = r & 1023;
  const float* zp = z + (size_t)n * 262144 + hw;
  const float a = aws[r];
  float bestv = FLT_MAX;
  int besti = 0x7fffffff;
  for (int ci = sub; ci < m; ci += 4) {
    const float2 p = gcand[(size_t)r * NSLOT + ci];
    if (p.x > lim) continue;
    const int k = __float_as_int(p.y);
    const float* ep = emb + (size_t)k * 256;
    float dot = 0.0f;
#pragma unroll 8
    for (int d = 0; d < 256; ++d) dot = fmaf(zp[(size_t)d * 1024], ep[d], dot);
    float s = fmaf(-2.0f, dot, a);  // fl(a - 2*dot)
    s = s + cws[k];                 // fl(s + c)
    if (s < bestv || (s == bestv && k < besti)) {
      bestv = s;
      besti = k;
    }
  }
#pragma unroll
  for (int off = 1; off < 4; off <<= 1) {
    const float ov = __shfl_xor(bestv, off);
    const int oi = __shfl_xor(besti, off);
    if (ov < bestv || (ov == bestv && oi < besti)) {
      bestv = ov;
      besti = oi;
    }
  }
  if (sub == 0) {
    idxws[r] = besti;
    out[OUT_IDX_OFF + r] = (float)besti;
  }
  float c = (sub == 0) ? bestv : 0.0f;
#pragma unroll
  for (int off = 1; off < 64; off <<= 1) c += __shfl_xor(c, off);
  if ((threadIdx.x & 63) == 0)
    atomicAdd(&out[OUT_LOSS_OFF], c * (1.02f / 16777216.0f));
}

// ---------------------------------------------------------------------------
// k_out2: pure z_q gather-write (unchanged). Overwrites all d_out scratch.
// ---------------------------------------------------------------------------
__global__ __launch_bounds__(256) void k_out2(const float* __restrict__ emb,
                                              const int* __restrict__ idxws,
                                              float* __restrict__ out) {
  __shared__ float zq[32][257];
  __shared__ int sidx[32];
  const int t = threadIdx.x;
  const int p0 = blockIdx.x << 5;
  const int n = p0 >> 10, hw0 = p0 & 1023;
  if (t < 32) sidx[t] = idxws[p0 + t];
  __syncthreads();
#pragma unroll
  for (int it = 0; it < 8; ++it) {
    const int i = t + (it << 8);
    const int p = i >> 6;
    const int q = (i & 63) << 2;
    const float4 v = *(const float4*)&emb[(size_t)sidx[p] * 256 + q];
    zq[p][q] = v.x;
    zq[p][q + 1] = v.y;
    zq[p][q + 2] = v.z;
    zq[p][q + 3] = v.w;
  }
  __syncthreads();
  const int p = t & 31, d0 = t >> 5;
  float* ob = out + (size_t)n * 262144 + hw0 + p;
#pragma unroll
  for (int dd = 0; dd < 32; ++dd) {
    const int d = (dd << 3) + d0;
    ob[(size_t)d * 1024] = zq[p][d];
  }
}

// ---------------------------------------------------------------------------
extern "C" void kernel_launch(void* const* d_in, const int* in_sizes, int n_in,
                              void* d_out, int out_size, void* d_ws,
                              size_t ws_size, hipStream_t stream) {
  const float* z = (const float*)d_in[0];
  const float* emb = (const float*)d_in[1];
  float* out = (float*)d_out;

  // ws layout: E2 bf16 [1024*256] | cws [1024] | aws [65536] | idx [65536]
  unsigned short* E2 = (unsigned short*)d_ws;
  float* cws = (float*)(E2 + 262144);
  float* aws = cws + 1024;
  int* idxws = (int*)(aws + 65536);
  // scratch in d_out's z_q region (k_out2 overwrites it last):
  unsigned short* A2 = (unsigned short*)d_out;
  float2* gcand = (float2*)(out + CAND_OFF);
  int* gmin = (int*)(out + GMIN_OFF);
  int* gcnt = (int*)(out + GCNT_OFF);

  hipMemsetAsync((char*)d_out + (size_t)OUT_LOSS_OFF * 4, 0, 4, stream);
  hipMemsetAsync(gmin, 0x7f, 65536 * 4, stream);  // 0x7f7f7f7f ~ +inf
  hipMemsetAsync(gcnt, 0, 65536 * 4, stream);

  k_prep<<<dim3(1024), dim3(256), 0, stream>>>(emb, E2, cws);
  k_cvt4<<<dim3(1024), dim3(256), 0, stream>>>(z, A2, aws);
  k_gemm8<<<dim3(4096), dim3(256), 0, stream>>>(A2, E2, cws, aws, gmin, gcnt,
                                                gcand);
  k_finish<<<dim3(1024), dim3(256), 0, stream>>>(z, emb, cws, aws, gmin, gcnt,
                                                 gcand, idxws, out);
  k_out2<<<dim3(2048), dim3(256), 0, stream>>>(emb, idxws, out);
}

// Round 7
// 295.868 us; speedup vs baseline: 1.5510x; 1.2310x over previous
//
#include <hip/hip_runtime.h>
#include <hip/hip_bf16.h>
#include <float.h>

// z: (64, 256, 32, 32) fp32 ; emb: (1024, 256) fp32
// M = 65536 pixels, D = 256, K = 1024 codes
// out: [z_q (16777216 f)] [indices as float (65536)] [vq_loss (1)]
#define OUT_IDX_OFF 16777216
#define OUT_LOSS_OFF 16842752
// scratch inside d_out's z_q region (overwritten by k_out at the end):
// A2 bf16 (row-major [pixel][256]): floats [0, 8388608)
// cand pairs (s,k) float2: floats [8388608, 12582912)  65536 rows x 32 slots
// gmin (int-punned f32):   floats [12582912, 13107200)
// gcnt (int):              floats [13107200, 13631488)
#define CAND_OFF 8388608
#define GMIN_OFF 12582912
#define GCNT_OFF 13107200
#define NSLOT 32
#define DELTA 2.0e-3f

typedef __attribute__((ext_vector_type(8))) short short8;
typedef __attribute__((ext_vector_type(4))) float f32x4;

static __device__ __forceinline__ unsigned short f2bf(float f) {
  union { __hip_bfloat16 h; unsigned short u; } cv;
  cv.h = __float2bfloat16(f);
  return cv.u;
}

// ---------------------------------------------------------------------------
// P1: emb -> E2 bf16 [1024 codes][256 d] row-major + exact cws (proven).
// Also absorbs the three memsets (gmin=+inf pattern, gcnt=0, loss=0):
// k_prep has exactly 262144 threads; the first 65536 init one row each.
// Stream-ordered before k_gemm9/k_finish -> no race.
// ---------------------------------------------------------------------------
__global__ __launch_bounds__(256) void k_prep(const float* __restrict__ emb,
                                              unsigned short* __restrict__ E2,
                                              float* __restrict__ cws,
                                              int* __restrict__ gmin,
                                              int* __restrict__ gcnt,
                                              float* __restrict__ out) {
  const int k = blockIdx.x, d = threadIdx.x;
  const int tid = (k << 8) + d;
  if (tid < 65536) {
    gmin[tid] = 0x7f7f7f7f;  // ~ +inf (same pattern as old memset)
    gcnt[tid] = 0;
  }
  if (tid == 0) out[OUT_LOSS_OFF] = 0.0f;
  const float v = emb[k * 256 + d];
  __shared__ float red[256];
  __shared__ unsigned short row[256];
  row[d] = f2bf(v);
  red[d] = v * v;
  __syncthreads();
  for (int s = 128; s > 0; s >>= 1) {
    if (d < s) red[d] += red[d + s];
    __syncthreads();
  }
  if (d == 0) cws[k] = red[0];
  if (d < 32) ((short8*)&E2[k * 256])[d] = ((short8*)row)[d];
}

// ---------------------------------------------------------------------------
// k_cvt4: FUSED z->A2 bf16 (row-major) + exact aws (k_a absorbed). Proven in
// R4 (rest-of-pipeline -17us, bit-exact aws). Unchanged.
// ---------------------------------------------------------------------------
__global__ __launch_bounds__(256) void k_cvt4(const float* __restrict__ z,
                                              unsigned short* __restrict__ A2,
                                              float* __restrict__ aws) {
#pragma clang fp contract(off)
  __shared__ float tile[64][65];
  __shared__ float red2[128];
  const int t = threadIdx.x;
  const int p0 = blockIdx.x << 6;
  const int n = p0 >> 10, hw0 = p0 & 1023;
  const float* zb = z + (size_t)n * 262144 + hw0;
  const int hwl = (t & 15) << 2;
  const int dlb = t >> 4;  // 0..15
  const int row = t & 63, h = (t >> 6) & 1;  // acc assignment (t<128)
  const int pl = t >> 2, c = t & 3;          // A2-store assignment

  float4 v[4];
#pragma unroll
  for (int i = 0; i < 4; ++i)
    v[i] = *(const float4*)&zb[(size_t)(dlb + i * 16) * 1024 + hwl];

  float acc[8];

  for (int dt = 0; dt < 4; ++dt) {
    if (dt) __syncthreads();  // previous-phase readers done
#pragma unroll
    for (int i = 0; i < 4; ++i) {
      const int dl = dlb + i * 16;
      tile[hwl + 0][dl] = v[i].x;
      tile[hwl + 1][dl] = v[i].y;
      tile[hwl + 2][dl] = v[i].z;
      tile[hwl + 3][dl] = v[i].w;
    }
    __syncthreads();
    if (dt < 3) {  // prefetch next slab into regs (overlaps phase below)
      const float* zb2 = zb + (size_t)(dt + 1) * 65536;
#pragma unroll
      for (int i = 0; i < 4; ++i)
        v[i] = *(const float4*)&zb2[(size_t)(dlb + i * 16) * 1024 + hwl];
    }
    // A2 store (verbatim k_cvt2 store phase, d0 = dt*64)
    unsigned short* dst = &A2[(size_t)(p0 + pl) * 256 + dt * 64];
#pragma unroll
    for (int hh = 0; hh < 2; ++hh) {
      const int ch = c + hh * 4;
      unsigned short tmp[8];
#pragma unroll
      for (int j = 0; j < 8; ++j) tmp[j] = f2bf(tile[pl][ch * 8 + j]);
      *(short8*)&dst[ch * 8] = *(short8*)tmp;
    }
    // aws chain: wave0 (h=0) consumes slabs 0,1; wave1 (h=1) slabs 2,3
    if (t < 128 && (dt >> 1) == h) {
      if ((dt & 1) == 0) {
#pragma unroll
        for (int j = 0; j < 8; ++j) {
          const float x = tile[row][j];
          acc[j] = x * x;  // g = 0 init
        }
        for (int g = 1; g < 8; ++g)
#pragma unroll
          for (int j = 0; j < 8; ++j) {
            const float x = tile[row][g * 8 + j];
            const float p = x * x;
            acc[j] = acc[j] + p;
          }
      } else {
        for (int g = 8; g < 16; ++g)
#pragma unroll
          for (int j = 0; j < 8; ++j) {
            const float x = tile[row][(g - 8) * 8 + j];
            const float p = x * x;
            acc[j] = acc[j] + p;
          }
      }
    }
  }
  if (t < 128) {
    const float s = ((acc[0] + acc[1]) + (acc[2] + acc[3])) +
                    ((acc[4] + acc[5]) + (acc[6] + acc[7]));
    red2[t] = s;
  }
  __syncthreads();
  if (t < 64) aws[p0 + t] = red2[t] + red2[t + 64];  // fl(s_h0 + s_h1), as k_a
}

// ---------------------------------------------------------------------------
// k_gemm9: VERBATIM restore of R2's k_gemm4 (proven 96.5us, VGPR 64 + 64
// AGPR acc, zero spill, FETCH 19MB). R5/R6 lesson: the 128-reg/wave footprint
// caps residency at 4 waves/SIMD regardless of LDS, and any launch-bound or
// epilogue change that fights that caused scratch spill (217-542MB writes).
// This shape is the register-ceiling optimum of the 128x128 structure.
//   - 4096 blocks, XCD-chunked swizzle (ck fastest per XCD -> A-panel L2-hot)
//   - global_load_lds staging, pre-swizzled source granule (m173)
//   - a_l/c_l LDS preload; epilogue score chain bit-identical across rounds
// ---------------------------------------------------------------------------
__global__ __launch_bounds__(256, 4) void k_gemm9(
    const unsigned short* __restrict__ A2, const unsigned short* __restrict__ E2,
    const float* __restrict__ cws, const float* __restrict__ aws,
    int* __restrict__ gmin, int* __restrict__ gcnt,
    float2* __restrict__ gcand) {
  __shared__ __align__(16) unsigned short As[128 * 64];
  __shared__ __align__(16) unsigned short Bs[128 * 64];
  __shared__ float a_l[128], c_l[128], rmkt[256], bmin[128];

  const int t = threadIdx.x;
  const int lane = t & 63;
  const int wave = __builtin_amdgcn_readfirstlane(t >> 6);
  const int wr = wave >> 1, wc = wave & 1;
  const int quad = lane >> 4, l15 = lane & 15;
  const int swa = l15 & 7;

  // XCD-chunked swizzle (grid 4096 % 8 == 0 -> bijective)
  const int bid = blockIdx.x;
  const int L = ((bid & 7) << 9) + (bid >> 3);
  const int rb = L >> 3, ck = L & 7;
  const int r0 = rb << 7, k0 = ck << 7;

  if (t < 128) {
    a_l[t] = aws[r0 + t];
    c_l[t] = cws[k0 + t];
  }

  // staging geometry: round i covers 16B-granules G = i*256 + t of the
  // [128 rows][8 granules] kt-tile; row = G>>3, physical granule gpos = G&7,
  // source granule gpos^(row&7) (involution; matches fragment-read swizzle).
  const int srow = t >> 3;  // rows advance by 32 per round
  const int gpos = t & 7;

  f32x4 acc[4][4];
#pragma unroll
  for (int a = 0; a < 4; ++a)
#pragma unroll
    for (int b = 0; b < 4; ++b) acc[a][b] = (f32x4)(0.0f);

  for (int kt = 0; kt < 4; ++kt) {
    if (kt) __syncthreads();  // waves done reading previous tiles
#pragma unroll
    for (int i = 0; i < 4; ++i) {
      const int row = (i << 5) + srow;
      const int gsrc = gpos ^ (row & 7);
      const unsigned short* sa =
          A2 + (((size_t)(r0 + row)) << 8) + (kt << 6) + (gsrc << 3);
      __builtin_amdgcn_global_load_lds(
          (const __attribute__((address_space(1))) void*)sa,
          (__attribute__((address_space(3))) void*)(As + (i << 11) +
                                                    (wave << 9)),
          16, 0, 0);
      const unsigned short* sb =
          E2 + (((size_t)(k0 + row)) << 8) + (kt << 6) + (gsrc << 3);
      __builtin_amdgcn_global_load_lds(
          (const __attribute__((address_space(1))) void*)sb,
          (__attribute__((address_space(3))) void*)(Bs + (i << 11) +
                                                    (wave << 9)),
          16, 0, 0);
    }
    __syncthreads();  // vmcnt drained -> tiles ready
#pragma unroll
    for (int ks = 0; ks < 2; ++ks) {
      short8 af[4], bf[4];
#pragma unroll
      for (int tr = 0; tr < 4; ++tr)
        af[tr] = *(const short8*)&As[(wr * 64 + tr * 16 + l15) * 64 +
                                     (((ks * 4 + quad) ^ swa) << 3)];
#pragma unroll
      for (int tc = 0; tc < 4; ++tc)
        bf[tc] = *(const short8*)&Bs[(wc * 64 + tc * 16 + l15) * 64 +
                                     (((ks * 4 + quad) ^ swa) << 3)];
#pragma unroll
      for (int tr = 0; tr < 4; ++tr)
#pragma unroll
        for (int tc = 0; tc < 4; ++tc)
          acc[tr][tc] = __builtin_amdgcn_mfma_f32_16x16x32_bf16(
              af[tr], bf[tc], acc[tr][tc], 0, 0, 0);
    }
  }

  // epilogue pass 1: chunk-local per-row min (verbatim)
#pragma unroll
  for (int tr = 0; tr < 4; ++tr)
#pragma unroll
    for (int rg = 0; rg < 4; ++rg) {
      const int rloc = wr * 64 + tr * 16 + quad * 4 + rg;
      const float av = a_l[rloc];
      float mn = FLT_MAX;
#pragma unroll
      for (int tc = 0; tc < 4; ++tc) {
        const int cloc = wc * 64 + tc * 16 + l15;
        const float s = av + fmaf(-2.0f, acc[tr][tc][rg], c_l[cloc]);
        mn = fminf(mn, s);
      }
      mn = fminf(mn, __shfl_xor(mn, 1));
      mn = fminf(mn, __shfl_xor(mn, 2));
      mn = fminf(mn, __shfl_xor(mn, 4));
      mn = fminf(mn, __shfl_xor(mn, 8));
      if (l15 == 0) rmkt[rloc * 2 + wc] = mn;
    }
  __syncthreads();
  if (t < 128) {
    const float m = fminf(rmkt[t * 2], rmkt[t * 2 + 1]);
    const int old = atomicMin(&gmin[r0 + t], __float_as_int(m));
    bmin[t] = fminf(m, __int_as_float(old));  // bits monotone for s>0
  }
  __syncthreads();
  // epilogue pass 2: append candidates within DELTA of tightened min
#pragma unroll
  for (int tr = 0; tr < 4; ++tr)
#pragma unroll
    for (int rg = 0; rg < 4; ++rg) {
      const int rloc = wr * 64 + tr * 16 + quad * 4 + rg;
      const float av = a_l[rloc];
      const float lim = bmin[rloc] + DELTA;
#pragma unroll
      for (int tc = 0; tc < 4; ++tc) {
        const int cloc = wc * 64 + tc * 16 + l15;
        const float s = av + fmaf(-2.0f, acc[tr][tc][rg], c_l[cloc]);
        if (s <= lim) {
          const int pos = atomicAdd(&gcnt[r0 + rloc], 1);
          if (pos < NSLOT)
            gcand[(size_t)(r0 + rloc) * NSLOT + pos] =
                make_float2(s, __int_as_float(k0 + cloc));
        }
      }
    }
}

// ---------------------------------------------------------------------------
// k_finish v2: 4 lanes per row, exact rescore chain UNCHANGED (bit-identical
// scores -> identical indices), quad shuffle-reduce with strict-< + lowest-k.
// Also accumulates vq_loss: winner's s IS ||z-e||^2 for that row.
// ---------------------------------------------------------------------------
__global__ __launch_bounds__(256) void k_finish(
    const float* __restrict__ z, const float* __restrict__ emb,
    const float* __restrict__ cws, const float* __restrict__ aws,
    const int* __restrict__ gmin, const int* __restrict__ gcnt,
    const float2* __restrict__ gcand, int* __restrict__ idxws,
    float* __restrict__ out) {
  const int tid = (blockIdx.x << 8) + threadIdx.x;
  const int r = tid >> 2, sub = tid & 3;
  const float lim = __int_as_float(gmin[r]) + DELTA;
  int m = gcnt[r];
  if (m > NSLOT) m = NSLOT;
  const int n = r >> 10, hw = r & 1023;
  const float* zp = z + (size_t)n * 262144 + hw;
  const float a = aws[r];
  float bestv = FLT_MAX;
  int besti = 0x7fffffff;
  for (int ci = sub; ci < m; ci += 4) {
    const float2 p = gcand[(size_t)r * NSLOT + ci];
    if (p.x > lim) continue;
    const int k = __float_as_int(p.y);
    const float* ep = emb + (size_t)k * 256;
    float dot = 0.0f;
#pragma unroll 8
    for (int d = 0; d < 256; ++d) dot = fmaf(zp[(size_t)d * 1024], ep[d], dot);
    float s = fmaf(-2.0f, dot, a);  // fl(a - 2*dot)
    s = s + cws[k];                 // fl(s + c)
    if (s < bestv || (s == bestv && k < besti)) {
      bestv = s;
      besti = k;
    }
  }
#pragma unroll
  for (int off = 1; off < 4; off <<= 1) {
    const float ov = __shfl_xor(bestv, off);
    const int oi = __shfl_xor(besti, off);
    if (ov < bestv || (ov == bestv && oi < besti)) {
      bestv = ov;
      besti = oi;
    }
  }
  if (sub == 0) {
    idxws[r] = besti;
    out[OUT_IDX_OFF + r] = (float)besti;
  }
  float c = (sub == 0) ? bestv : 0.0f;
#pragma unroll
  for (int off = 1; off < 64; off <<= 1) c += __shfl_xor(c, off);
  if ((threadIdx.x & 63) == 0)
    atomicAdd(&out[OUT_LOSS_OFF], c * (1.02f / 16777216.0f));
}

// ---------------------------------------------------------------------------
// k_out2: pure z_q gather-write (unchanged). Overwrites all d_out scratch.
// ---------------------------------------------------------------------------
__global__ __launch_bounds__(256) void k_out2(const float* __restrict__ emb,
                                              const int* __restrict__ idxws,
                                              float* __restrict__ out) {
  __shared__ float zq[32][257];
  __shared__ int sidx[32];
  const int t = threadIdx.x;
  const int p0 = blockIdx.x << 5;
  const int n = p0 >> 10, hw0 = p0 & 1023;
  if (t < 32) sidx[t] = idxws[p0 + t];
  __syncthreads();
#pragma unroll
  for (int it = 0; it < 8; ++it) {
    const int i = t + (it << 8);
    const int p = i >> 6;
    const int q = (i & 63) << 2;
    const float4 v = *(const float4*)&emb[(size_t)sidx[p] * 256 + q];
    zq[p][q] = v.x;
    zq[p][q + 1] = v.y;
    zq[p][q + 2] = v.z;
    zq[p][q + 3] = v.w;
  }
  __syncthreads();
  const int p = t & 31, d0 = t >> 5;
  float* ob = out + (size_t)n * 262144 + hw0 + p;
#pragma unroll
  for (int dd = 0; dd < 32; ++dd) {
    const int d = (dd << 3) + d0;
    ob[(size_t)d * 1024] = zq[p][d];
  }
}

// ---------------------------------------------------------------------------
extern "C" void kernel_launch(void* const* d_in, const int* in_sizes, int n_in,
                              void* d_out, int out_size, void* d_ws,
                              size_t ws_size, hipStream_t stream) {
  const float* z = (const float*)d_in[0];
  const float* emb = (const float*)d_in[1];
  float* out = (float*)d_out;

  // ws layout: E2 bf16 [1024*256] | cws [1024] | aws [65536] | idx [65536]
  unsigned short* E2 = (unsigned short*)d_ws;
  float* cws = (float*)(E2 + 262144);
  float* aws = cws + 1024;
  int* idxws = (int*)(aws + 65536);
  // scratch in d_out's z_q region (k_out2 overwrites it last):
  unsigned short* A2 = (unsigned short*)d_out;
  float2* gcand = (float2*)(out + CAND_OFF);
  int* gmin = (int*)(out + GMIN_OFF);
  int* gcnt = (int*)(out + GCNT_OFF);

  // all inits folded into k_prep (3 memset launches removed)
  k_prep<<<dim3(1024), dim3(256), 0, stream>>>(emb, E2, cws, gmin, gcnt, out);
  k_cvt4<<<dim3(1024), dim3(256), 0, stream>>>(z, A2, aws);
  k_gemm9<<<dim3(4096), dim3(256), 0, stream>>>(A2, E2, cws, aws, gmin, gcnt,
                                                gcand);
  k_finish<<<dim3(1024), dim3(256), 0, stream>>>(z, emb, cws, aws, gmin, gcnt,
                                                 gcand, idxws, out);
  k_out2<<<dim3(2048), dim3(256), 0, stream>>>(emb, idxws, out);
}